// Round 7
// baseline (361.439 us; speedup 1.0000x reference)
//
#include <hip/hip_runtime.h>

typedef unsigned short u16;
typedef unsigned int u32;
typedef unsigned char u8;
typedef long i64;
typedef float f4 __attribute__((ext_vector_type(4)));
typedef int i32x8 __attribute__((ext_vector_type(8)));

#define CDIM 768
#define NPROJ 5376
#define KFF 3840   // combined K for final gemm: 768 (attn) + 3072 (mlp)
#define NTOK 16384

// ---------------- fp8 e4m3 (OCP) conversion helpers, HW cvt when available
__device__ __forceinline__ u8 f2fp8(float f) {
#if __has_builtin(__builtin_amdgcn_cvt_pk_fp8_f32)
    return (u8)(__builtin_amdgcn_cvt_pk_fp8_f32(f, f, 0, false) & 0xff);
#else
    u32 u = __float_as_uint(f);
    u32 s = (u >> 24) & 0x80u;
    float a = fabsf(f);
    a = fminf(a, 448.f);
    if (a < 0.015625f) return (u8)(s | (u32)(a * 512.f + 0.5f));
    u32 b = __float_as_uint(a);
    b += 0x0007FFFFu + ((b >> 20) & 1u);
    u32 e = b >> 23, m = (b >> 20) & 7u;
    u32 code = ((e - 120u) << 3) | m;
    if (code > 0x7Eu) code = 0x7Eu;
    return (u8)(s | code);
#endif
}
__device__ __forceinline__ u32 pk4_fp8(float a, float b, float c, float d) {
#if __has_builtin(__builtin_amdgcn_cvt_pk_fp8_f32)
    u32 lo = (u32)__builtin_amdgcn_cvt_pk_fp8_f32(a, b, 0, false);
    return (u32)__builtin_amdgcn_cvt_pk_fp8_f32(c, d, lo, true);
#else
    return (u32)f2fp8(a) | ((u32)f2fp8(b) << 8) | ((u32)f2fp8(c) << 16) | ((u32)f2fp8(d) << 24);
#endif
}
__device__ __forceinline__ float fp8_to_f32(u32 v) {
#if __has_builtin(__builtin_amdgcn_cvt_f32_fp8)
    return __builtin_amdgcn_cvt_f32_fp8((int)v, 0);
#else
    u32 s = v >> 7, e = (v >> 3) & 15u, m = v & 7u;
    float mag = e ? __uint_as_float(((e + 120u) << 23) | (m << 20))
                  : (float)m * 0.001953125f;
    return s ? -mag : mag;
#endif
}

__device__ __forceinline__ float wsum64(float v) {
#pragma unroll
    for (int m = 32; m > 0; m >>= 1) v += __shfl_xor(v, m, 64);
    return v;
}
__device__ __forceinline__ void gl_lds16(const u8* g, u8* l) {
    __builtin_amdgcn_global_load_lds((__attribute__((address_space(1))) u32*)g,
                                     (__attribute__((address_space(3))) u32*)l,
                                     16, 0, 0);
}

// ---------------- fused prep: 3 weight transpose+casts and the x LayerNorm,
// all independent, in ONE launch (removes 3 launch gaps).
// blocks [0,4032): Wqkv -> WqkvT ; [4032,4608): Wout -> BT2[:,0:768]
// blocks [4608,6912): Wmlp -> BT2[:,768:3840] ; [6912,11008): ln_rows
__global__ __launch_bounds__(256) void prep_fused(
    const float* __restrict__ Wqkv, u8* __restrict__ WqkvT,
    const float* __restrict__ Wout, const float* __restrict__ Wmlp,
    u8* __restrict__ BT2,
    const float* __restrict__ x, const float* __restrict__ normw,
    u8* __restrict__ xn) {
    __shared__ float t[32][33];
    const int bid = blockIdx.x;
    const int tid = threadIdx.x;
    if (bid < 6912) {
        const float* src; u8* dst; int R, Cc, dstride, doff, bx, by;
        if (bid < 4032) {
            src = Wqkv; dst = WqkvT; R = CDIM; Cc = NPROJ; dstride = CDIM; doff = 0;
            bx = bid % 168; by = bid / 168;
        } else if (bid < 4608) {
            const int b2 = bid - 4032;
            src = Wout; dst = BT2; R = CDIM; Cc = CDIM; dstride = KFF; doff = 0;
            bx = b2 % 24; by = b2 / 24;
        } else {
            const int b2 = bid - 4608;
            src = Wmlp; dst = BT2; R = 3072; Cc = CDIM; dstride = KFF; doff = 768;
            bx = b2 % 24; by = b2 / 24;
        }
        const int c0 = bx * 32, r0 = by * 32;
        const int tx = tid & 31, ty = tid >> 5;
#pragma unroll
        for (int i = 0; i < 32; i += 8) {
            int r = r0 + ty + i, c = c0 + tx;
            if (r < R && c < Cc) t[ty + i][tx] = src[(size_t)r * Cc + c];
        }
        __syncthreads();
#pragma unroll
        for (int i = 0; i < 32; i += 8) {
            int c = c0 + ty + i, r = r0 + tx;
            if (r < R && c < Cc) dst[(size_t)c * dstride + doff + r] = f2fp8(t[tx][ty + i]);
        }
    } else {
        // ---- LayerNorm over C=768, 4 rows/block, one wave per row, fp8 out
        const int row = (bid - 6912) * 4 + (tid >> 6);
        const int lane = tid & 63;
        const f4* xr = (const f4*)(x + (size_t)row * CDIM);
        const f4* wr = (const f4*)normw;
        f4 v[3];
        float s = 0.f, s2 = 0.f;
#pragma unroll
        for (int i = 0; i < 3; ++i) {
            v[i] = xr[lane + 64 * i];
#pragma unroll
            for (int j = 0; j < 4; ++j) { s += v[i][j]; s2 += v[i][j] * v[i][j]; }
        }
        s = wsum64(s); s2 = wsum64(s2);
        float mu = s * (1.f / 768.f);
        float var = s2 * (1.f / 768.f) - mu * mu;
        float rs = rsqrtf(var + 1e-5f);
        u32* xo = (u32*)(xn + (size_t)row * CDIM);
#pragma unroll
        for (int i = 0; i < 3; ++i) {
            f4 wv = wr[lane + 64 * i];
            xo[lane + 64 * i] = pk4_fp8((v[i][0] - mu) * rs * wv[0], (v[i][1] - mu) * rs * wv[1],
                                        (v[i][2] - mu) * rs * wv[2], (v[i][3] - mu) * rs * wv[3]);
        }
    }
}

// ---------------- MX-fp8 MFMA GEMM (unit scales), A (MxK) fp8, B^T (NxK) fp8.
// Proven round-0 K-loop (122 us, MfmaUtil 24%) kept UNTOUCHED.
// ROUND-7: XCD swizzle REMOVED (round-6 evidence: it TRIPLED FETCH_SIZE
// 67->184 MB and cost 21 us -> the hardware's dispatch->XCD mapping does not
// match the round-robin assumption; default order has better L2 locality).
// KEPT from round-6: MODE 0 fused per-head qk LayerNorm in the epilogue
// (wave's 64 cols = one head; intra-quad shfl_xor reduce; qnw/knw via
// xres/gamma slots). LN on pre-quantization f32, once per token.
// MODE 0: proj epilogue (+bqkv; q,k cols LN'd; v plain; ff fast-gelu -> A2)
// MODE 1: final epilogue (+bout+bmlp, out = x + gamma*acc, fp32)
template <int MODE>
__global__ __launch_bounds__(256) void gemm_bt(
    const u8* __restrict__ A, const u8* __restrict__ B, int M, int N, int K,
    const float* __restrict__ bias0, const float* __restrict__ bias1,
    const float* __restrict__ xres, const float* __restrict__ gamma,
    u8* __restrict__ oqkv, u8* __restrict__ off, float* __restrict__ ofin) {
    __shared__ __align__(16) u8 As[128 * 128];
    __shared__ __align__(16) u8 Bs[128 * 128];
    const int tid = threadIdx.x;
    const int wid = tid >> 6, lane = tid & 63;
    const int wm = wid >> 1, wn = wid & 1;
    const int quad = lane >> 4, l16 = lane & 15;
    const int m0 = blockIdx.y * 128, n0 = blockIdx.x * 128;

    f4 acc[4][4] = {};

    // staging: each glds16 call = 8 rows x 128B. 4 A-calls + 4 B-calls per wave.
    const int rl = lane >> 3;
    const int csw = ((lane & 7) ^ rl) * 16;           // swizzled source byte offset
    const u8* aptr[4]; const u8* bptr[4];
    u8* alds[4]; u8* blds[4];
#pragma unroll
    for (int jj = 0; jj < 4; ++jj) {
        const int r0 = wid * 32 + jj * 8;
        aptr[jj] = A + (size_t)(m0 + r0 + rl) * K + csw;
        bptr[jj] = B + (size_t)(n0 + r0 + rl) * K + csw;
        alds[jj] = As + r0 * 128;
        blds[jj] = Bs + r0 * 128;
    }
    const int swl = l16 & 7;                          // read-side swizzle (16B-chunk units)

    for (int kt = 0; kt < K; kt += 128) {
#pragma unroll
        for (int jj = 0; jj < 4; ++jj) {
            gl_lds16(aptr[jj] + kt, alds[jj]);
            gl_lds16(bptr[jj] + kt, blds[jj]);
        }
        __syncthreads();
        const int c0 = ((2 * quad) ^ swl) * 16;
        const int c1 = ((2 * quad + 1) ^ swl) * 16;
        i32x8 af[4], bfv[4];
#pragma unroll
        for (int mi = 0; mi < 4; ++mi) {
            const u8* base = As + (wm * 64 + mi * 16 + l16) * 128;
            uint4 lo = *(const uint4*)(base + c0);
            uint4 hi = *(const uint4*)(base + c1);
            af[mi][0] = lo.x; af[mi][1] = lo.y; af[mi][2] = lo.z; af[mi][3] = lo.w;
            af[mi][4] = hi.x; af[mi][5] = hi.y; af[mi][6] = hi.z; af[mi][7] = hi.w;
        }
#pragma unroll
        for (int ni = 0; ni < 4; ++ni) {
            const u8* base = Bs + (wn * 64 + ni * 16 + l16) * 128;
            uint4 lo = *(const uint4*)(base + c0);
            uint4 hi = *(const uint4*)(base + c1);
            bfv[ni][0] = lo.x; bfv[ni][1] = lo.y; bfv[ni][2] = lo.z; bfv[ni][3] = lo.w;
            bfv[ni][4] = hi.x; bfv[ni][5] = hi.y; bfv[ni][6] = hi.z; bfv[ni][7] = hi.w;
        }
#pragma unroll
        for (int mi = 0; mi < 4; ++mi)
#pragma unroll
            for (int ni = 0; ni < 4; ++ni)
                acc[mi][ni] = __builtin_amdgcn_mfma_scale_f32_16x16x128_f8f6f4(
                    af[mi], bfv[ni], acc[mi][ni], 0, 0, 0, 127, 0, 127);
        __syncthreads();
    }

    const int cbase = n0 + wn * 64;                   // wave's 64-col (one-head) base
#pragma unroll
    for (int mi = 0; mi < 4; ++mi) {
        const int rowb = m0 + wm * 64 + mi * 16 + quad * 4;
        if (MODE == 0) {
            if (cbase < 1536) {
                // ---- q/k: fused per-head LN (wave holds the full 64-ch head row)
                const float* hw = (cbase < 768) ? xres : gamma;   // qnw : knw
                float hwv[4], bc[4];
#pragma unroll
                for (int ni = 0; ni < 4; ++ni) {
                    hwv[ni] = hw[ni * 16 + l16];
                    bc[ni] = bias0[cbase + ni * 16 + l16];
                }
#pragma unroll
                for (int r = 0; r < 4; ++r) {
                    float v[4]; float s1 = 0.f, s2 = 0.f;
#pragma unroll
                    for (int ni = 0; ni < 4; ++ni) {
                        v[ni] = acc[mi][ni][r] + bc[ni];
                        s1 += v[ni]; s2 += v[ni] * v[ni];
                    }
#pragma unroll
                    for (int mk = 1; mk <= 8; mk <<= 1) {
                        s1 += __shfl_xor(s1, mk, 64);
                        s2 += __shfl_xor(s2, mk, 64);
                    }
                    const float mu = s1 * (1.f / 64.f);
                    const float rs = rsqrtf(s2 * (1.f / 64.f) - mu * mu + 1e-5f);
                    const size_t m = (size_t)(rowb + r);
#pragma unroll
                    for (int ni = 0; ni < 4; ++ni)
                        oqkv[m * 2304 + cbase + ni * 16 + l16] =
                            f2fp8((v[ni] - mu) * rs * hwv[ni]);
                }
            } else if (cbase < 2304) {
                // ---- v: plain quantize
#pragma unroll
                for (int ni = 0; ni < 4; ++ni) {
                    const int col = cbase + ni * 16 + l16;
                    const float bcv = bias0[col];
#pragma unroll
                    for (int r = 0; r < 4; ++r)
                        oqkv[(size_t)(rowb + r) * 2304 + col] = f2fp8(acc[mi][ni][r] + bcv);
                }
            } else {
                // ---- ff: fast gelu -> A2
#pragma unroll
                for (int ni = 0; ni < 4; ++ni) {
                    const int col = cbase + ni * 16 + l16;
                    const float bcv = bias0[col];
#pragma unroll
                    for (int r = 0; r < 4; ++r) {
                        float vv = acc[mi][ni][r] + bcv;
                        // fast gelu: x*sigmoid(1.5957691216x + 0.0713548162x^3)
                        float u2 = vv * (-1.5957691216f) - 0.0713548162f * vv * vv * vv;
                        float g = vv / (1.f + __expf(u2));
                        off[(size_t)(rowb + r) * KFF + 768 + (col - 2304)] = f2fp8(g);
                    }
                }
            }
        } else {
#pragma unroll
            for (int ni = 0; ni < 4; ++ni) {
                const int col = cbase + ni * 16 + l16;
                const float bcv = bias0[col] + bias1[col];
                const float gm = gamma[col];
#pragma unroll
                for (int r = 0; r < 4; ++r) {
                    const size_t m = (size_t)(rowb + r);
                    float vv = acc[mi][ni][r] + bcv;
                    ofin[m * CDIM + col] = xres[m * CDIM + col] + gm * vv;
                }
            }
        }
    }
}

// ---------------- fp8 MFMA axial attention: block = (b, line j, head he), 4 waves.
// LN lives in gemm0 epilogue -> staging is simple vector loads (round-6 form).
// ROUND-7: XCD swizzle removed (same evidence as gemm_bt).
// phase 0 = row-j attention, phase 1 = column-j; register-accumulated, one
// fp8 write to A2[tok(b,i,j)]. S^T = K.Q^T (softmax per-lane + 2 quad
// shuffles), P->LDS (u32 packed), O = P.V with V^T built at load.
// All LDS tiles padded to 72B rows -> conflict-free 8B frag reads, no swizzle.
__global__ __launch_bounds__(256) void axial_attn_mfma(const u8* __restrict__ qkv,
                                                       u8* __restrict__ A2) {
    __shared__ __align__(16) u8 Qs[64 * 72];
    __shared__ __align__(16) u8 Ks[64 * 72];
    __shared__ __align__(16) u8 Vt[64 * 72];   // V^T[c][k]
    __shared__ __align__(16) u8 Ps[64 * 72];   // P[q][k]

    const int bx = (int)blockIdx.x;
    const int he = bx % 12;
    const int j = (bx / 12) & 63;
    const int b = bx / (12 * 64);
    const int tid = threadIdx.x;
    const int w = tid >> 6, lane = tid & 63;
    const int l16 = lane & 15, quad = lane >> 4;
    const int qb = w * 16;

    f4 acc_o[4] = {};

    // staging thread mapping: row sr = tid>>2 (0..63), 16B segment sc = (tid&3)*16
    const int sr = tid >> 2;
    const int sc = (tid & 3) * 16;

    for (int phase = 0; phase < 2; ++phase) {
        const size_t tok = (phase == 0) ? (size_t)((b * 64 + j) * 64 + sr)
                                        : (size_t)((b * 64 + sr) * 64 + j);
        const u8* src = qkv + tok * 2304 + he * 64 + sc;
        {
            uint4 qv = *(const uint4*)(src);
            uint4 kv = *(const uint4*)(src + 768);
            *(uint4*)(Qs + sr * 72 + sc) = qv;
            *(uint4*)(Ks + sr * 72 + sc) = kv;
        }
        // V transposed: thread owns (k = sr, c in [sc, sc+16))
        {
            uint4 vv = *(const uint4*)(src + 1536);
            const u8* vb = (const u8*)&vv;
#pragma unroll
            for (int i = 0; i < 16; ++i) Vt[(sc + i) * 72 + sr] = vb[i];
        }
        __syncthreads();

        // ---- S^T tiles: D[m=k-idx][n=q], this wave's q-cols = qb..qb+15
        f4 st[4] = {};
#pragma unroll
        for (int kt = 0; kt < 2; ++kt) {
            const int boff = (kt * 4 + quad) * 8;
            const i64 bq = *(const i64*)(Qs + (qb + l16) * 72 + boff);
#pragma unroll
            for (int mt = 0; mt < 4; ++mt) {
                const i64 ak = *(const i64*)(Ks + (mt * 16 + l16) * 72 + boff);
                st[mt] = __builtin_amdgcn_mfma_f32_16x16x32_fp8_fp8(ak, bq, st[mt], 0, 0, 0);
            }
        }

        // ---- softmax over k (= m axis): per-lane 16 values + cross-quad shuffles
        float sv[16];
        float mx = -1e30f;
#pragma unroll
        for (int mt = 0; mt < 4; ++mt)
#pragma unroll
            for (int r = 0; r < 4; ++r) {
                const float s = st[mt][r] * 0.125f;
                sv[mt * 4 + r] = s;
                mx = fmaxf(mx, s);
            }
        mx = fmaxf(mx, __shfl_xor(mx, 16, 64));
        mx = fmaxf(mx, __shfl_xor(mx, 32, 64));
        float sm = 0.f;
#pragma unroll
        for (int i = 0; i < 16; ++i) { sv[i] = __expf(sv[i] - mx); sm += sv[i]; }
        sm += __shfl_xor(sm, 16, 64);
        sm += __shfl_xor(sm, 32, 64);
        const float inv = 1.f / sm;

        // ---- write P[q][k] (transpose out of C-layout), packed u32 stores
#pragma unroll
        for (int mt = 0; mt < 4; ++mt) {
            const int kbase = mt * 16 + quad * 4;
            *(u32*)(Ps + (qb + l16) * 72 + kbase) =
                pk4_fp8(sv[mt * 4] * inv, sv[mt * 4 + 1] * inv,
                        sv[mt * 4 + 2] * inv, sv[mt * 4 + 3] * inv);
        }
        __syncthreads();

        // ---- O += P.V : m-tile = this wave's q rows, n-tiles over c
#pragma unroll
        for (int kt = 0; kt < 2; ++kt) {
            const int boff = (kt * 4 + quad) * 8;
            const i64 ap = *(const i64*)(Ps + (qb + l16) * 72 + boff);
#pragma unroll
            for (int nt = 0; nt < 4; ++nt) {
                const i64 bv = *(const i64*)(Vt + (nt * 16 + l16) * 72 + boff);
                acc_o[nt] = __builtin_amdgcn_mfma_f32_16x16x32_fp8_fp8(ap, bv, acc_o[nt], 0, 0, 0);
            }
        }
        __syncthreads();   // protect tiles before next phase reload
    }

    // ---- store: q = qb + quad*4 + r, c = nt*16 + l16
#pragma unroll
    for (int nt = 0; nt < 4; ++nt)
#pragma unroll
        for (int r = 0; r < 4; ++r) {
            const int q = qb + quad * 4 + r;
            const int c = nt * 16 + l16;
            A2[((size_t)((b * 64 + q) * 64 + j)) * KFF + he * 64 + c] = f2fp8(acc_o[nt][r]);
        }
}

extern "C" void kernel_launch(void* const* d_in, const int* in_sizes, int n_in,
                              void* d_out, int out_size, void* d_ws, size_t ws_size,
                              hipStream_t stream) {
    const float* x = (const float*)d_in[0];
    const float* normw = (const float*)d_in[1];
    const float* Wqkv = (const float*)d_in[2];
    const float* bqkv = (const float*)d_in[3];
    const float* qnw = (const float*)d_in[4];
    const float* knw = (const float*)d_in[5];
    const float* Wout = (const float*)d_in[6];
    const float* bout = (const float*)d_in[7];
    const float* Wmlp = (const float*)d_in[8];
    const float* bmlp = (const float*)d_in[9];
    const float* gamma = (const float*)d_in[10];
    float* out = (float*)d_out;

    char* ws = (char*)d_ws;
    u8* xn = (u8*)ws;    ws += (size_t)NTOK * CDIM;
    u8* WqkvT = (u8*)ws; ws += (size_t)NPROJ * CDIM;
    u8* BT2 = (u8*)ws;   ws += (size_t)CDIM * KFF;
    u8* qkv = (u8*)ws;   ws += (size_t)NTOK * 2304;
    u8* A2 = (u8*)ws;    ws += (size_t)NTOK * KFF;

    // fused prep: weight transposes -> fp8 B^T buffers, plus LN(x) -> fp8
    prep_fused<<<11008, 256, 0, stream>>>(Wqkv, WqkvT, Wout, Wmlp, BT2, x, normw, xn);
    // proj GEMM: q,k (fused per-head LN), v -> qkv buffer; gelu(ff) -> A2[:, 768:3840]
    // (qnw/knw ride in the xres/gamma parameter slots for MODE 0)
    gemm_bt<0><<<dim3(NPROJ / 128, NTOK / 128), 256, 0, stream>>>(
        xn, WqkvT, NTOK, NPROJ, CDIM, bqkv, nullptr, qnw, knw, qkv, A2, nullptr);
    // both axial attentions -> A2[:, 0:768]
    axial_attn_mfma<<<3072, 256, 0, stream>>>(qkv, A2);
    // final fused GEMM: out = x + gamma * (A2 @ [WoutT|WmlpT] + bout + bmlp)
    gemm_bt<1><<<dim3(CDIM / 128, NTOK / 128), 256, 0, stream>>>(
        A2, BT2, NTOK, CDIM, KFF, bout, bmlp, x, gamma, nullptr, nullptr, out);
}

// Round 8
// 349.299 us; speedup vs baseline: 1.0348x; 1.0348x over previous
//
#include <hip/hip_runtime.h>

typedef unsigned short u16;
typedef unsigned int u32;
typedef unsigned char u8;
typedef long i64;
typedef float f4 __attribute__((ext_vector_type(4)));
typedef int i32x8 __attribute__((ext_vector_type(8)));

#define CDIM 768
#define NPROJ 5376
#define KFF 3840   // combined K for final gemm: 768 (attn) + 3072 (mlp)
#define NTOK 16384

// ---------------- fp8 e4m3 (OCP) conversion helpers, HW cvt when available
__device__ __forceinline__ u8 f2fp8(float f) {
#if __has_builtin(__builtin_amdgcn_cvt_pk_fp8_f32)
    return (u8)(__builtin_amdgcn_cvt_pk_fp8_f32(f, f, 0, false) & 0xff);
#else
    u32 u = __float_as_uint(f);
    u32 s = (u >> 24) & 0x80u;
    float a = fabsf(f);
    a = fminf(a, 448.f);
    if (a < 0.015625f) return (u8)(s | (u32)(a * 512.f + 0.5f));
    u32 b = __float_as_uint(a);
    b += 0x0007FFFFu + ((b >> 20) & 1u);
    u32 e = b >> 23, m = (b >> 20) & 7u;
    u32 code = ((e - 120u) << 3) | m;
    if (code > 0x7Eu) code = 0x7Eu;
    return (u8)(s | code);
#endif
}
__device__ __forceinline__ u32 pk4_fp8(float a, float b, float c, float d) {
#if __has_builtin(__builtin_amdgcn_cvt_pk_fp8_f32)
    u32 lo = (u32)__builtin_amdgcn_cvt_pk_fp8_f32(a, b, 0, false);
    return (u32)__builtin_amdgcn_cvt_pk_fp8_f32(c, d, lo, true);
#else
    return (u32)f2fp8(a) | ((u32)f2fp8(b) << 8) | ((u32)f2fp8(c) << 16) | ((u32)f2fp8(d) << 24);
#endif
}
__device__ __forceinline__ float fp8_to_f32(u32 v) {
#if __has_builtin(__builtin_amdgcn_cvt_f32_fp8)
    return __builtin_amdgcn_cvt_f32_fp8((int)v, 0);
#else
    u32 s = v >> 7, e = (v >> 3) & 15u, m = v & 7u;
    float mag = e ? __uint_as_float(((e + 120u) << 23) | (m << 20))
                  : (float)m * 0.001953125f;
    return s ? -mag : mag;
#endif
}

__device__ __forceinline__ float wsum64(float v) {
#pragma unroll
    for (int m = 32; m > 0; m >>= 1) v += __shfl_xor(v, m, 64);
    return v;
}
__device__ __forceinline__ void gl_lds16(const u8* g, u8* l) {
    __builtin_amdgcn_global_load_lds((__attribute__((address_space(1))) u32*)g,
                                     (__attribute__((address_space(3))) u32*)l,
                                     16, 0, 0);
}

// ---------------- fused prep: 3 weight transpose+casts and the x LayerNorm,
// all independent, in ONE launch (removes 3 launch gaps).
// blocks [0,4032): Wqkv -> WqkvT ; [4032,4608): Wout -> BT2[:,0:768]
// blocks [4608,6912): Wmlp -> BT2[:,768:3840] ; [6912,11008): ln_rows
__global__ __launch_bounds__(256) void prep_fused(
    const float* __restrict__ Wqkv, u8* __restrict__ WqkvT,
    const float* __restrict__ Wout, const float* __restrict__ Wmlp,
    u8* __restrict__ BT2,
    const float* __restrict__ x, const float* __restrict__ normw,
    u8* __restrict__ xn) {
    __shared__ float t[32][33];
    const int bid = blockIdx.x;
    const int tid = threadIdx.x;
    if (bid < 6912) {
        const float* src; u8* dst; int R, Cc, dstride, doff, bx, by;
        if (bid < 4032) {
            src = Wqkv; dst = WqkvT; R = CDIM; Cc = NPROJ; dstride = CDIM; doff = 0;
            bx = bid % 168; by = bid / 168;
        } else if (bid < 4608) {
            const int b2 = bid - 4032;
            src = Wout; dst = BT2; R = CDIM; Cc = CDIM; dstride = KFF; doff = 0;
            bx = b2 % 24; by = b2 / 24;
        } else {
            const int b2 = bid - 4608;
            src = Wmlp; dst = BT2; R = 3072; Cc = CDIM; dstride = KFF; doff = 768;
            bx = b2 % 24; by = b2 / 24;
        }
        const int c0 = bx * 32, r0 = by * 32;
        const int tx = tid & 31, ty = tid >> 5;
#pragma unroll
        for (int i = 0; i < 32; i += 8) {
            int r = r0 + ty + i, c = c0 + tx;
            if (r < R && c < Cc) t[ty + i][tx] = src[(size_t)r * Cc + c];
        }
        __syncthreads();
#pragma unroll
        for (int i = 0; i < 32; i += 8) {
            int c = c0 + ty + i, r = r0 + tx;
            if (r < R && c < Cc) dst[(size_t)c * dstride + doff + r] = f2fp8(t[tx][ty + i]);
        }
    } else {
        // ---- LayerNorm over C=768, 4 rows/block, one wave per row, fp8 out
        const int row = (bid - 6912) * 4 + (tid >> 6);
        const int lane = tid & 63;
        const f4* xr = (const f4*)(x + (size_t)row * CDIM);
        const f4* wr = (const f4*)normw;
        f4 v[3];
        float s = 0.f, s2 = 0.f;
#pragma unroll
        for (int i = 0; i < 3; ++i) {
            v[i] = xr[lane + 64 * i];
#pragma unroll
            for (int j = 0; j < 4; ++j) { s += v[i][j]; s2 += v[i][j] * v[i][j]; }
        }
        s = wsum64(s); s2 = wsum64(s2);
        float mu = s * (1.f / 768.f);
        float var = s2 * (1.f / 768.f) - mu * mu;
        float rs = rsqrtf(var + 1e-5f);
        u32* xo = (u32*)(xn + (size_t)row * CDIM);
#pragma unroll
        for (int i = 0; i < 3; ++i) {
            f4 wv = wr[lane + 64 * i];
            xo[lane + 64 * i] = pk4_fp8((v[i][0] - mu) * rs * wv[0], (v[i][1] - mu) * rs * wv[1],
                                        (v[i][2] - mu) * rs * wv[2], (v[i][3] - mu) * rs * wv[3]);
        }
    }
}

// ---------------- MX-fp8 MFMA GEMM (unit scales), A (MxK) fp8, B^T (NxK) fp8.
// Proven round-0 K-loop (122 us, MfmaUtil 24%) kept UNTOUCHED. NO XCD swizzle
// (round-6 evidence: tripled FETCH 67->184 MB, +21 us; default dispatch order
// has the better L2 locality for this grid shape).
// MODE 0 epilogue: fused per-head qk LayerNorm (wave's 64 cols = one head;
// intra-quad shfl_xor reduce; qnw/knw via xres/gamma slots); v plain
// quantize; ff fast-gelu -> A2. MODE 1: +bout+bmlp, out = x + gamma*acc.
template <int MODE>
__global__ __launch_bounds__(256) void gemm_bt(
    const u8* __restrict__ A, const u8* __restrict__ B, int M, int N, int K,
    const float* __restrict__ bias0, const float* __restrict__ bias1,
    const float* __restrict__ xres, const float* __restrict__ gamma,
    u8* __restrict__ oqkv, u8* __restrict__ off, float* __restrict__ ofin) {
    __shared__ __align__(16) u8 As[128 * 128];
    __shared__ __align__(16) u8 Bs[128 * 128];
    const int tid = threadIdx.x;
    const int wid = tid >> 6, lane = tid & 63;
    const int wm = wid >> 1, wn = wid & 1;
    const int quad = lane >> 4, l16 = lane & 15;
    const int m0 = blockIdx.y * 128, n0 = blockIdx.x * 128;

    f4 acc[4][4] = {};

    // staging: each glds16 call = 8 rows x 128B. 4 A-calls + 4 B-calls per wave.
    const int rl = lane >> 3;
    const int csw = ((lane & 7) ^ rl) * 16;           // swizzled source byte offset
    const u8* aptr[4]; const u8* bptr[4];
    u8* alds[4]; u8* blds[4];
#pragma unroll
    for (int jj = 0; jj < 4; ++jj) {
        const int r0 = wid * 32 + jj * 8;
        aptr[jj] = A + (size_t)(m0 + r0 + rl) * K + csw;
        bptr[jj] = B + (size_t)(n0 + r0 + rl) * K + csw;
        alds[jj] = As + r0 * 128;
        blds[jj] = Bs + r0 * 128;
    }
    const int swl = l16 & 7;                          // read-side swizzle (16B-chunk units)

    for (int kt = 0; kt < K; kt += 128) {
#pragma unroll
        for (int jj = 0; jj < 4; ++jj) {
            gl_lds16(aptr[jj] + kt, alds[jj]);
            gl_lds16(bptr[jj] + kt, blds[jj]);
        }
        __syncthreads();
        const int c0 = ((2 * quad) ^ swl) * 16;
        const int c1 = ((2 * quad + 1) ^ swl) * 16;
        i32x8 af[4], bfv[4];
#pragma unroll
        for (int mi = 0; mi < 4; ++mi) {
            const u8* base = As + (wm * 64 + mi * 16 + l16) * 128;
            uint4 lo = *(const uint4*)(base + c0);
            uint4 hi = *(const uint4*)(base + c1);
            af[mi][0] = lo.x; af[mi][1] = lo.y; af[mi][2] = lo.z; af[mi][3] = lo.w;
            af[mi][4] = hi.x; af[mi][5] = hi.y; af[mi][6] = hi.z; af[mi][7] = hi.w;
        }
#pragma unroll
        for (int ni = 0; ni < 4; ++ni) {
            const u8* base = Bs + (wn * 64 + ni * 16 + l16) * 128;
            uint4 lo = *(const uint4*)(base + c0);
            uint4 hi = *(const uint4*)(base + c1);
            bfv[ni][0] = lo.x; bfv[ni][1] = lo.y; bfv[ni][2] = lo.z; bfv[ni][3] = lo.w;
            bfv[ni][4] = hi.x; bfv[ni][5] = hi.y; bfv[ni][6] = hi.z; bfv[ni][7] = hi.w;
        }
#pragma unroll
        for (int mi = 0; mi < 4; ++mi)
#pragma unroll
            for (int ni = 0; ni < 4; ++ni)
                acc[mi][ni] = __builtin_amdgcn_mfma_scale_f32_16x16x128_f8f6f4(
                    af[mi], bfv[ni], acc[mi][ni], 0, 0, 0, 127, 0, 127);
        __syncthreads();
    }

    const int cbase = n0 + wn * 64;                   // wave's 64-col (one-head) base
#pragma unroll
    for (int mi = 0; mi < 4; ++mi) {
        const int rowb = m0 + wm * 64 + mi * 16 + quad * 4;
        if (MODE == 0) {
            if (cbase < 1536) {
                // ---- q/k: fused per-head LN (wave holds the full 64-ch head row)
                const float* hw = (cbase < 768) ? xres : gamma;   // qnw : knw
                float hwv[4], bc[4];
#pragma unroll
                for (int ni = 0; ni < 4; ++ni) {
                    hwv[ni] = hw[ni * 16 + l16];
                    bc[ni] = bias0[cbase + ni * 16 + l16];
                }
#pragma unroll
                for (int r = 0; r < 4; ++r) {
                    float v[4]; float s1 = 0.f, s2 = 0.f;
#pragma unroll
                    for (int ni = 0; ni < 4; ++ni) {
                        v[ni] = acc[mi][ni][r] + bc[ni];
                        s1 += v[ni]; s2 += v[ni] * v[ni];
                    }
#pragma unroll
                    for (int mk = 1; mk <= 8; mk <<= 1) {
                        s1 += __shfl_xor(s1, mk, 64);
                        s2 += __shfl_xor(s2, mk, 64);
                    }
                    const float mu = s1 * (1.f / 64.f);
                    const float rs = rsqrtf(s2 * (1.f / 64.f) - mu * mu + 1e-5f);
                    const size_t m = (size_t)(rowb + r);
#pragma unroll
                    for (int ni = 0; ni < 4; ++ni)
                        oqkv[m * 2304 + cbase + ni * 16 + l16] =
                            f2fp8((v[ni] - mu) * rs * hwv[ni]);
                }
            } else if (cbase < 2304) {
                // ---- v: plain quantize
#pragma unroll
                for (int ni = 0; ni < 4; ++ni) {
                    const int col = cbase + ni * 16 + l16;
                    const float bcv = bias0[col];
#pragma unroll
                    for (int r = 0; r < 4; ++r)
                        oqkv[(size_t)(rowb + r) * 2304 + col] = f2fp8(acc[mi][ni][r] + bcv);
                }
            } else {
                // ---- ff: fast gelu -> A2
#pragma unroll
                for (int ni = 0; ni < 4; ++ni) {
                    const int col = cbase + ni * 16 + l16;
                    const float bcv = bias0[col];
#pragma unroll
                    for (int r = 0; r < 4; ++r) {
                        float vv = acc[mi][ni][r] + bcv;
                        // fast gelu: x*sigmoid(1.5957691216x + 0.0713548162x^3)
                        float u2 = vv * (-1.5957691216f) - 0.0713548162f * vv * vv * vv;
                        float g = vv / (1.f + __expf(u2));
                        off[(size_t)(rowb + r) * KFF + 768 + (col - 2304)] = f2fp8(g);
                    }
                }
            }
        } else {
#pragma unroll
            for (int ni = 0; ni < 4; ++ni) {
                const int col = cbase + ni * 16 + l16;
                const float bcv = bias0[col] + bias1[col];
                const float gm = gamma[col];
#pragma unroll
                for (int r = 0; r < 4; ++r) {
                    const size_t m = (size_t)(rowb + r);
                    float vv = acc[mi][ni][r] + bcv;
                    ofin[m * CDIM + col] = xres[m * CDIM + col] + gm * vv;
                }
            }
        }
    }
}

// ---------------- fp8 MFMA axial attention: block = (b, line j, head he), 4 waves.
// ROUND-8: XCD swizzle RE-APPLIED to attn ONLY. Evidence (r6 vs r7 diff):
// with swizzle attn ran ~40 us faster; without it each XCD's resident blocks
// span the whole (b,j) space, so phase-1's scattered column reads thrash L2
// (per-XCD working set = full 37.7 MB qkv). Swizzled: each XCD owns 384
// consecutive bx = 32 (b,j) pairs x 12 he -> ~4.7 MB footprint ~ L2-sized.
// (GEMMs stay UNswizzled - swizzle tripled their FETCH, r6.)
// phase 0 = row-j attention, phase 1 = column-j; register-accumulated, one
// fp8 write to A2[tok(b,i,j)]. S^T = K.Q^T (softmax per-lane + 2 quad
// shuffles), P->LDS (u32 packed), O = P.V with V^T built at load.
// All LDS tiles padded to 72B rows -> conflict-free 8B frag reads, no swizzle.
__global__ __launch_bounds__(256) void axial_attn_mfma(const u8* __restrict__ qkv,
                                                       u8* __restrict__ A2) {
    __shared__ __align__(16) u8 Qs[64 * 72];
    __shared__ __align__(16) u8 Ks[64 * 72];
    __shared__ __align__(16) u8 Vt[64 * 72];   // V^T[c][k]
    __shared__ __align__(16) u8 Ps[64 * 72];   // P[q][k]

    int bx = (int)blockIdx.x;
    bx = (bx & 7) * 384 + (bx >> 3);           // bijective XCD swizzle (3072/8)
    const int he = bx % 12;
    const int j = (bx / 12) & 63;
    const int b = bx / (12 * 64);
    const int tid = threadIdx.x;
    const int w = tid >> 6, lane = tid & 63;
    const int l16 = lane & 15, quad = lane >> 4;
    const int qb = w * 16;

    f4 acc_o[4] = {};

    // staging thread mapping: row sr = tid>>2 (0..63), 16B segment sc = (tid&3)*16
    const int sr = tid >> 2;
    const int sc = (tid & 3) * 16;

    for (int phase = 0; phase < 2; ++phase) {
        const size_t tok = (phase == 0) ? (size_t)((b * 64 + j) * 64 + sr)
                                        : (size_t)((b * 64 + sr) * 64 + j);
        const u8* src = qkv + tok * 2304 + he * 64 + sc;
        {
            uint4 qv = *(const uint4*)(src);
            uint4 kv = *(const uint4*)(src + 768);
            *(uint4*)(Qs + sr * 72 + sc) = qv;
            *(uint4*)(Ks + sr * 72 + sc) = kv;
        }
        // V transposed: thread owns (k = sr, c in [sc, sc+16))
        {
            uint4 vv = *(const uint4*)(src + 1536);
            const u8* vb = (const u8*)&vv;
#pragma unroll
            for (int i = 0; i < 16; ++i) Vt[(sc + i) * 72 + sr] = vb[i];
        }
        __syncthreads();

        // ---- S^T tiles: D[m=k-idx][n=q], this wave's q-cols = qb..qb+15
        f4 st[4] = {};
#pragma unroll
        for (int kt = 0; kt < 2; ++kt) {
            const int boff = (kt * 4 + quad) * 8;
            const i64 bq = *(const i64*)(Qs + (qb + l16) * 72 + boff);
#pragma unroll
            for (int mt = 0; mt < 4; ++mt) {
                const i64 ak = *(const i64*)(Ks + (mt * 16 + l16) * 72 + boff);
                st[mt] = __builtin_amdgcn_mfma_f32_16x16x32_fp8_fp8(ak, bq, st[mt], 0, 0, 0);
            }
        }

        // ---- softmax over k (= m axis): per-lane 16 values + cross-quad shuffles
        float sv[16];
        float mx = -1e30f;
#pragma unroll
        for (int mt = 0; mt < 4; ++mt)
#pragma unroll
            for (int r = 0; r < 4; ++r) {
                const float s = st[mt][r] * 0.125f;
                sv[mt * 4 + r] = s;
                mx = fmaxf(mx, s);
            }
        mx = fmaxf(mx, __shfl_xor(mx, 16, 64));
        mx = fmaxf(mx, __shfl_xor(mx, 32, 64));
        float sm = 0.f;
#pragma unroll
        for (int i = 0; i < 16; ++i) { sv[i] = __expf(sv[i] - mx); sm += sv[i]; }
        sm += __shfl_xor(sm, 16, 64);
        sm += __shfl_xor(sm, 32, 64);
        const float inv = 1.f / sm;

        // ---- write P[q][k] (transpose out of C-layout), packed u32 stores
#pragma unroll
        for (int mt = 0; mt < 4; ++mt) {
            const int kbase = mt * 16 + quad * 4;
            *(u32*)(Ps + (qb + l16) * 72 + kbase) =
                pk4_fp8(sv[mt * 4] * inv, sv[mt * 4 + 1] * inv,
                        sv[mt * 4 + 2] * inv, sv[mt * 4 + 3] * inv);
        }
        __syncthreads();

        // ---- O += P.V : m-tile = this wave's q rows, n-tiles over c
#pragma unroll
        for (int kt = 0; kt < 2; ++kt) {
            const int boff = (kt * 4 + quad) * 8;
            const i64 ap = *(const i64*)(Ps + (qb + l16) * 72 + boff);
#pragma unroll
            for (int nt = 0; nt < 4; ++nt) {
                const i64 bv = *(const i64*)(Vt + (nt * 16 + l16) * 72 + boff);
                acc_o[nt] = __builtin_amdgcn_mfma_f32_16x16x32_fp8_fp8(ap, bv, acc_o[nt], 0, 0, 0);
            }
        }
        __syncthreads();   // protect tiles before next phase reload
    }

    // ---- store: q = qb + quad*4 + r, c = nt*16 + l16
#pragma unroll
    for (int nt = 0; nt < 4; ++nt)
#pragma unroll
        for (int r = 0; r < 4; ++r) {
            const int q = qb + quad * 4 + r;
            const int c = nt * 16 + l16;
            A2[((size_t)((b * 64 + q) * 64 + j)) * KFF + he * 64 + c] = f2fp8(acc_o[nt][r]);
        }
}

extern "C" void kernel_launch(void* const* d_in, const int* in_sizes, int n_in,
                              void* d_out, int out_size, void* d_ws, size_t ws_size,
                              hipStream_t stream) {
    const float* x = (const float*)d_in[0];
    const float* normw = (const float*)d_in[1];
    const float* Wqkv = (const float*)d_in[2];
    const float* bqkv = (const float*)d_in[3];
    const float* qnw = (const float*)d_in[4];
    const float* knw = (const float*)d_in[5];
    const float* Wout = (const float*)d_in[6];
    const float* bout = (const float*)d_in[7];
    const float* Wmlp = (const float*)d_in[8];
    const float* bmlp = (const float*)d_in[9];
    const float* gamma = (const float*)d_in[10];
    float* out = (float*)d_out;

    char* ws = (char*)d_ws;
    u8* xn = (u8*)ws;    ws += (size_t)NTOK * CDIM;
    u8* WqkvT = (u8*)ws; ws += (size_t)NPROJ * CDIM;
    u8* BT2 = (u8*)ws;   ws += (size_t)CDIM * KFF;
    u8* qkv = (u8*)ws;   ws += (size_t)NTOK * 2304;
    u8* A2 = (u8*)ws;    ws += (size_t)NTOK * KFF;

    // fused prep: weight transposes -> fp8 B^T buffers, plus LN(x) -> fp8
    prep_fused<<<11008, 256, 0, stream>>>(Wqkv, WqkvT, Wout, Wmlp, BT2, x, normw, xn);
    // proj GEMM: q,k (fused per-head LN), v -> qkv buffer; gelu(ff) -> A2[:, 768:3840]
    // (qnw/knw ride in the xres/gamma parameter slots for MODE 0)
    gemm_bt<0><<<dim3(NPROJ / 128, NTOK / 128), 256, 0, stream>>>(
        xn, WqkvT, NTOK, NPROJ, CDIM, bqkv, nullptr, qnw, knw, qkv, A2, nullptr);
    // both axial attentions -> A2[:, 0:768]
    axial_attn_mfma<<<3072, 256, 0, stream>>>(qkv, A2);
    // final fused GEMM: out = x + gamma * (A2 @ [WoutT|WmlpT] + bout + bmlp)
    gemm_bt<1><<<dim3(CDIM / 128, NTOK / 128), 256, 0, stream>>>(
        A2, BT2, NTOK, CDIM, KFF, bout, bmlp, x, gamma, nullptr, nullptr, out);
}